// Round 1
// baseline (210.394 us; speedup 1.0000x reference)
//
#include <hip/hip_runtime.h>

// GroupWiseAgg: MVS group-wise correlation cost volume.
// features: (NVIEW=4, B=1, C=32, H=112, W=144) fp32
// proj_matrices: (B=1, NVIEW=4, 2, 4, 4) fp32   [0]=extrinsic E, [1]=intrinsic K
// depth: (B=1, D=48, H=112, W=144) fp32
// out: (B=1, G=8, D=48, H=112, W=144) fp32
//
// out[g,d,h,w] = (1/12) * sum_{v=1..3} sum_{c in group g} warp_v(fea_v)[c,d,h,w] * fea_0[c,h,w]

constexpr int NVIEW = 4;
constexpr int C     = 32;
constexpr int G     = 8;
constexpr int CPG   = C / G;      // 4
constexpr int D     = 48;
constexpr int H     = 112;
constexpr int W     = 144;
constexpr int HW    = H * W;      // 16128
constexpr int TOTAL = D * HW;     // 774144

// fold: P = [[K3x3 @ E[:3,:4]], [E row 3]]
__device__ inline void fold_mat(const float* pm, double out[16]) {
    const float* E = pm;        // extrinsic
    const float* K = pm + 16;   // intrinsic
    for (int i = 0; i < 3; ++i)
        for (int j = 0; j < 4; ++j) {
            double s = 0.0;
            for (int k = 0; k < 3; ++k) s += (double)K[i*4+k] * (double)E[k*4+j];
            out[i*4+j] = s;
        }
    for (int j = 0; j < 4; ++j) out[12+j] = (double)E[12+j];
}

// 4x4 inverse, Gauss-Jordan with partial pivoting (fp64; thread-0 only)
__device__ inline void inv4(const double A[16], double out[16]) {
    double M[4][8];
    for (int r = 0; r < 4; ++r) {
        for (int c = 0; c < 4; ++c) M[r][c] = A[r*4+c];
        for (int c = 0; c < 4; ++c) M[r][4+c] = (r == c) ? 1.0 : 0.0;
    }
    for (int col = 0; col < 4; ++col) {
        int piv = col;
        double best = fabs(M[col][col]);
        for (int r = col+1; r < 4; ++r) {
            double v = fabs(M[r][col]);
            if (v > best) { best = v; piv = r; }
        }
        if (piv != col)
            for (int c = 0; c < 8; ++c) { double t = M[col][c]; M[col][c] = M[piv][c]; M[piv][c] = t; }
        double ip = 1.0 / M[col][col];
        for (int c = 0; c < 8; ++c) M[col][c] *= ip;
        for (int r = 0; r < 4; ++r) {
            if (r == col) continue;
            double f = M[r][col];
            if (f != 0.0)
                for (int c = 0; c < 8; ++c) M[r][c] -= f * M[col][c];
        }
    }
    for (int r = 0; r < 4; ++r)
        for (int c = 0; c < 4; ++c) out[r*4+c] = M[r][4+c];
}

__global__ __launch_bounds__(256) void gwc_kernel(
    const float* __restrict__ fea,    // (NVIEW, C, H, W)
    const float* __restrict__ proj,   // (NVIEW, 2, 4, 4)
    const float* __restrict__ depth,  // (D, H, W)
    float* __restrict__ out)          // (G, D, H, W)
{
    __shared__ float s_rt[(NVIEW-1)*12];   // per src view: rot[9], trans[3]

    if (threadIdx.x == 0) {
        double Pref[16], Pinv[16];
        fold_mat(proj, Pref);
        inv4(Pref, Pinv);
        for (int v = 1; v < NVIEW; ++v) {
            double Ps[16];
            fold_mat(proj + v*32, Ps);
            double Pr[16];
            for (int i = 0; i < 4; ++i)
                for (int j = 0; j < 4; ++j) {
                    double s = 0.0;
                    for (int k = 0; k < 4; ++k) s += Ps[i*4+k] * Pinv[k*4+j];
                    Pr[i*4+j] = s;
                }
            float* dst = s_rt + (v-1)*12;
            for (int i = 0; i < 3; ++i)
                for (int j = 0; j < 3; ++j) dst[i*3+j] = (float)Pr[i*4+j];
            for (int i = 0; i < 3; ++i) dst[9+i] = (float)Pr[i*4+3];
        }
    }
    __syncthreads();

    const int tid = blockIdx.x * blockDim.x + threadIdx.x;  // grid exactly covers TOTAL
    const int p   = tid % HW;
    const float dep = depth[tid];
    const float fx = (float)(p % W);
    const float fy = (float)(p / W);

    // reference features for this pixel (view 0), 32 channels
    float refv[C];
    #pragma unroll
    for (int c = 0; c < C; ++c) refv[c] = fea[c*HW + p];

    float acc[G];
    #pragma unroll
    for (int g = 0; g < G; ++g) acc[g] = 0.f;

    #pragma unroll
    for (int v = 1; v < NVIEW; ++v) {
        const float* rt = s_rt + (v-1)*12;
        const float X = fmaf(fmaf(rt[0], fx, fmaf(rt[1], fy, rt[2])), dep, rt[9]);
        const float Y = fmaf(fmaf(rt[3], fx, fmaf(rt[4], fy, rt[5])), dep, rt[10]);
        const float Z = fmaf(fmaf(rt[6], fx, fmaf(rt[7], fy, rt[8])), dep, rt[11]);
        const float px = X / Z;
        const float py = Y / Z;

        const float x0f = floorf(px), y0f = floorf(py);
        const float dx = px - x0f, dy = py - y0f;
        const int x0 = (int)x0f, y0 = (int)y0f;
        const int x1 = x0 + 1,  y1 = y0 + 1;

        float w00 = (1.f-dx)*(1.f-dy);
        float w10 = dx*(1.f-dy);
        float w01 = (1.f-dx)*dy;
        float w11 = dx*dy;

        const bool vx0 = (x0 >= 0) & (x0 < W);
        const bool vx1 = (x1 >= 0) & (x1 < W);
        const bool vy0 = (y0 >= 0) & (y0 < H);
        const bool vy1 = (y1 >= 0) & (y1 < H);
        const int xc0 = min(max(x0, 0), W-1), xc1 = min(max(x1, 0), W-1);
        const int yc0 = min(max(y0, 0), H-1), yc1 = min(max(y1, 0), H-1);
        if (!(vx0 && vy0)) w00 = 0.f;
        if (!(vx1 && vy0)) w10 = 0.f;
        if (!(vx0 && vy1)) w01 = 0.f;
        if (!(vx1 && vy1)) w11 = 0.f;

        const int o00 = yc0*W + xc0, o10 = yc0*W + xc1;
        const int o01 = yc1*W + xc0, o11 = yc1*W + xc1;

        const float* Fv = fea + v*(C*HW);
        #pragma unroll
        for (int c = 0; c < C; ++c) {
            const float* Fc = Fv + c*HW;
            const float s = w00*Fc[o00] + w10*Fc[o10] + w01*Fc[o01] + w11*Fc[o11];
            acc[c >> 2] = fmaf(s, refv[c], acc[c >> 2]);
        }
    }

    const float scale = 1.f / (float)(CPG * (NVIEW-1));   // 1/12
    #pragma unroll
    for (int g = 0; g < G; ++g)
        out[g*TOTAL + tid] = acc[g] * scale;
}

extern "C" void kernel_launch(void* const* d_in, const int* in_sizes, int n_in,
                              void* d_out, int out_size, void* d_ws, size_t ws_size,
                              hipStream_t stream) {
    const float* fea   = (const float*)d_in[0];
    const float* proj  = (const float*)d_in[1];
    const float* depth = (const float*)d_in[2];
    float* out = (float*)d_out;

    const int threads = 256;
    const int blocks  = TOTAL / threads;   // 3024, exact
    gwc_kernel<<<blocks, threads, 0, stream>>>(fea, proj, depth, out);
}

// Round 2
// 78.536 us; speedup vs baseline: 2.6789x; 2.6789x over previous
//
#include <hip/hip_runtime.h>

// GroupWiseAgg: MVS group-wise correlation cost volume.
// features: (NVIEW=4, C=32, H=112, W=144) fp32
// proj:     (NVIEW, 2, 4, 4) fp32  [0]=extrinsic E, [1]=intrinsic K
// depth:    (D=48, H=112, W=144) fp32
// out:      (G=8, D, H, W) fp32
//
// Strategy: transpose features to HWC in ws (128B per pixel), then
// 4 lanes per pixel each own 2 channel-chunks (= 2 groups), DCHUNK depths
// per thread. Tap loads become 64B-contiguous per 4-lane cluster.

constexpr int NVIEW = 4;
constexpr int C     = 32;
constexpr int G     = 8;
constexpr int D     = 48;
constexpr int H     = 112;
constexpr int W     = 144;
constexpr int HW    = H * W;        // 16128
constexpr int TOTAL = D * HW;       // 774144
constexpr int DCHUNK = 4;
constexpr int NDC    = D / DCHUNK;  // 12

// ---------- host-side matrix math helpers (device, thread-0 only) ----------
__device__ inline void fold_mat(const float* pm, double out[16]) {
    const float* E = pm;        // extrinsic
    const float* K = pm + 16;   // intrinsic
    for (int i = 0; i < 3; ++i)
        for (int j = 0; j < 4; ++j) {
            double s = 0.0;
            for (int k = 0; k < 3; ++k) s += (double)K[i*4+k] * (double)E[k*4+j];
            out[i*4+j] = s;
        }
    for (int j = 0; j < 4; ++j) out[12+j] = (double)E[12+j];
}

__device__ inline void inv4(const double A[16], double out[16]) {
    double M[4][8];
    for (int r = 0; r < 4; ++r) {
        for (int c = 0; c < 4; ++c) M[r][c] = A[r*4+c];
        for (int c = 0; c < 4; ++c) M[r][4+c] = (r == c) ? 1.0 : 0.0;
    }
    for (int col = 0; col < 4; ++col) {
        int piv = col;
        double best = fabs(M[col][col]);
        for (int r = col+1; r < 4; ++r) {
            double v = fabs(M[r][col]);
            if (v > best) { best = v; piv = r; }
        }
        if (piv != col)
            for (int c = 0; c < 8; ++c) { double t = M[col][c]; M[col][c] = M[piv][c]; M[piv][c] = t; }
        double ip = 1.0 / M[col][col];
        for (int c = 0; c < 8; ++c) M[col][c] *= ip;
        for (int r = 0; r < 4; ++r) {
            if (r == col) continue;
            double f = M[r][col];
            if (f != 0.0)
                for (int c = 0; c < 8; ++c) M[r][c] -= f * M[col][c];
        }
    }
    for (int r = 0; r < 4; ++r)
        for (int c = 0; c < 4; ++c) out[r*4+c] = M[r][4+c];
}

// compute rot/trans of src_proj @ inv(ref_proj) for v=1..3 into dst[36]
__device__ inline void compute_rt(const float* proj, float* dst) {
    double Pref[16], Pinv[16];
    fold_mat(proj, Pref);
    inv4(Pref, Pinv);
    for (int v = 1; v < NVIEW; ++v) {
        double Ps[16], Pr[16];
        fold_mat(proj + v*32, Ps);
        for (int i = 0; i < 4; ++i)
            for (int j = 0; j < 4; ++j) {
                double s = 0.0;
                for (int k = 0; k < 4; ++k) s += Ps[i*4+k] * Pinv[k*4+j];
                Pr[i*4+j] = s;
            }
        float* o = dst + (v-1)*12;
        for (int i = 0; i < 3; ++i)
            for (int j = 0; j < 3; ++j) o[i*3+j] = (float)Pr[i*4+j];
        for (int i = 0; i < 3; ++i) o[9+i] = (float)Pr[i*4+3];
    }
}

// ---------- transpose CHW -> HWC ----------
__global__ __launch_bounds__(256) void transpose_kernel(
    const float* __restrict__ fea, float* __restrict__ feaT)
{
    const int t = blockIdx.x * blockDim.x + threadIdx.x;  // v*HW + p
    const int v = t / HW;
    const int p = t - v * HW;
    const float* src = fea + v*(C*HW) + p;
    float vals[C];
    #pragma unroll
    for (int c = 0; c < C; ++c) vals[c] = src[c*HW];
    float4* dst = (float4*)(feaT + (size_t)t * C);
    #pragma unroll
    for (int q = 0; q < C/4; ++q)
        dst[q] = make_float4(vals[4*q], vals[4*q+1], vals[4*q+2], vals[4*q+3]);
}

// ---------- main kernel: HWC, 4 lanes/pixel, DCHUNK depths/thread ----------
__global__ __launch_bounds__(256) void gwc_main(
    const float* __restrict__ feaT,   // (NVIEW, HW, C)
    const float* __restrict__ proj,   // (NVIEW, 2, 4, 4)
    const float* __restrict__ depth,  // (D, HW)
    float* __restrict__ out)          // (G, D, HW)
{
    __shared__ float s_rt[(NVIEW-1)*12];
    if (threadIdx.x == 0) compute_rt(proj, s_rt);
    __syncthreads();

    const int tid = blockIdx.x * blockDim.x + threadIdx.x;
    const int l   = tid & 3;        // lane-in-cluster: owns groups l and l+4
    const int wid = tid >> 2;       // work item: (dc, p)
    const int p   = wid % HW;
    const int dc  = wid / HW;       // depth chunk [0, NDC)
    const float fx = (float)(p % W);
    const float fy = (float)(p / W);

    // ref features: chunks l and l+4 of pixel p (view 0)
    const float4 refA = *(const float4*)(feaT + (size_t)p*C + l*4);
    const float4 refB = *(const float4*)(feaT + (size_t)p*C + (l+4)*4);

    // hoist per-pixel rotated ray per view: X = rx*dep + tx
    float rx[3], ry[3], rz[3], tx[3], ty[3], tz[3];
    #pragma unroll
    for (int v = 0; v < 3; ++v) {
        const float* rt = s_rt + v*12;
        rx[v] = fmaf(rt[0], fx, fmaf(rt[1], fy, rt[2]));
        ry[v] = fmaf(rt[3], fx, fmaf(rt[4], fy, rt[5]));
        rz[v] = fmaf(rt[6], fx, fmaf(rt[7], fy, rt[8]));
        tx[v] = rt[9]; ty[v] = rt[10]; tz[v] = rt[11];
    }

    const float scale = 1.f / 12.f;

    for (int dd = 0; dd < DCHUNK; ++dd) {
        const int d    = dc * DCHUNK + dd;
        const int didx = d * HW + p;
        const float dep = depth[didx];

        float accA = 0.f, accB = 0.f;

        #pragma unroll
        for (int v = 0; v < 3; ++v) {
            const float X = fmaf(rx[v], dep, tx[v]);
            const float Y = fmaf(ry[v], dep, ty[v]);
            const float Z = fmaf(rz[v], dep, tz[v]);
            const float px = X / Z;
            const float py = Y / Z;

            const float x0f = floorf(px), y0f = floorf(py);
            const float dx = px - x0f, dy = py - y0f;
            const int x0 = (int)x0f, y0 = (int)y0f;
            const int x1 = x0 + 1,  y1 = y0 + 1;

            float w00 = (1.f-dx)*(1.f-dy);
            float w10 = dx*(1.f-dy);
            float w01 = (1.f-dx)*dy;
            float w11 = dx*dy;

            const bool vx0 = (x0 >= 0) & (x0 < W);
            const bool vx1 = (x1 >= 0) & (x1 < W);
            const bool vy0 = (y0 >= 0) & (y0 < H);
            const bool vy1 = (y1 >= 0) & (y1 < H);
            if (!(vx0 && vy0)) w00 = 0.f;
            if (!(vx1 && vy0)) w10 = 0.f;
            if (!(vx0 && vy1)) w01 = 0.f;
            if (!(vx1 && vy1)) w11 = 0.f;

            const int xc0 = min(max(x0, 0), W-1), xc1 = min(max(x1, 0), W-1);
            const int yc0 = min(max(y0, 0), H-1), yc1 = min(max(y1, 0), H-1);
            const int o00 = yc0*W + xc0, o10 = yc0*W + xc1;
            const int o01 = yc1*W + xc0, o11 = yc1*W + xc1;

            const float* base = feaT + (size_t)(v+1) * HW * C;
            const float4* t00 = (const float4*)(base + (size_t)o00*C);
            const float4* t10 = (const float4*)(base + (size_t)o10*C);
            const float4* t01 = (const float4*)(base + (size_t)o01*C);
            const float4* t11 = (const float4*)(base + (size_t)o11*C);

            // chunk A = q=l, chunk B = q=l+4
            const float4 a0 = t00[l],   a1 = t10[l],   a2 = t01[l],   a3 = t11[l];
            const float4 b0 = t00[l+4], b1 = t10[l+4], b2 = t01[l+4], b3 = t11[l+4];

            const float sAx = w00*a0.x + w10*a1.x + w01*a2.x + w11*a3.x;
            const float sAy = w00*a0.y + w10*a1.y + w01*a2.y + w11*a3.y;
            const float sAz = w00*a0.z + w10*a1.z + w01*a2.z + w11*a3.z;
            const float sAw = w00*a0.w + w10*a1.w + w01*a2.w + w11*a3.w;
            const float sBx = w00*b0.x + w10*b1.x + w01*b2.x + w11*b3.x;
            const float sBy = w00*b0.y + w10*b1.y + w01*b2.y + w11*b3.y;
            const float sBz = w00*b0.z + w10*b1.z + w01*b2.z + w11*b3.z;
            const float sBw = w00*b0.w + w10*b1.w + w01*b2.w + w11*b3.w;

            accA = fmaf(sAx, refA.x, fmaf(sAy, refA.y, fmaf(sAz, refA.z, fmaf(sAw, refA.w, accA))));
            accB = fmaf(sBx, refB.x, fmaf(sBy, refB.y, fmaf(sBz, refB.z, fmaf(sBw, refB.w, accB))));
        }

        __builtin_nontemporal_store(accA * scale, &out[l*TOTAL + didx]);
        __builtin_nontemporal_store(accB * scale, &out[(l+4)*TOTAL + didx]);
    }
}

// ---------- fallback (round-1 monolithic kernel) if ws too small ----------
__global__ __launch_bounds__(256) void gwc_fallback(
    const float* __restrict__ fea,
    const float* __restrict__ proj,
    const float* __restrict__ depth,
    float* __restrict__ out)
{
    __shared__ float s_rt[(NVIEW-1)*12];
    if (threadIdx.x == 0) compute_rt(proj, s_rt);
    __syncthreads();

    const int tid = blockIdx.x * blockDim.x + threadIdx.x;
    const int p   = tid % HW;
    const float dep = depth[tid];
    const float fx = (float)(p % W);
    const float fy = (float)(p / W);

    float refv[C];
    #pragma unroll
    for (int c = 0; c < C; ++c) refv[c] = fea[c*HW + p];

    float acc[G];
    #pragma unroll
    for (int g = 0; g < G; ++g) acc[g] = 0.f;

    #pragma unroll
    for (int v = 1; v < NVIEW; ++v) {
        const float* rt = s_rt + (v-1)*12;
        const float X = fmaf(fmaf(rt[0], fx, fmaf(rt[1], fy, rt[2])), dep, rt[9]);
        const float Y = fmaf(fmaf(rt[3], fx, fmaf(rt[4], fy, rt[5])), dep, rt[10]);
        const float Z = fmaf(fmaf(rt[6], fx, fmaf(rt[7], fy, rt[8])), dep, rt[11]);
        const float px = X / Z, py = Y / Z;
        const float x0f = floorf(px), y0f = floorf(py);
        const float dx = px - x0f, dy = py - y0f;
        const int x0 = (int)x0f, y0 = (int)y0f;
        const int x1 = x0 + 1,  y1 = y0 + 1;
        float w00 = (1.f-dx)*(1.f-dy), w10 = dx*(1.f-dy), w01 = (1.f-dx)*dy, w11 = dx*dy;
        const bool vx0 = (x0 >= 0) & (x0 < W), vx1 = (x1 >= 0) & (x1 < W);
        const bool vy0 = (y0 >= 0) & (y0 < H), vy1 = (y1 >= 0) & (y1 < H);
        if (!(vx0 && vy0)) w00 = 0.f;
        if (!(vx1 && vy0)) w10 = 0.f;
        if (!(vx0 && vy1)) w01 = 0.f;
        if (!(vx1 && vy1)) w11 = 0.f;
        const int xc0 = min(max(x0, 0), W-1), xc1 = min(max(x1, 0), W-1);
        const int yc0 = min(max(y0, 0), H-1), yc1 = min(max(y1, 0), H-1);
        const int o00 = yc0*W + xc0, o10 = yc0*W + xc1;
        const int o01 = yc1*W + xc0, o11 = yc1*W + xc1;
        const float* Fv = fea + v*(C*HW);
        #pragma unroll
        for (int c = 0; c < C; ++c) {
            const float* Fc = Fv + c*HW;
            const float s = w00*Fc[o00] + w10*Fc[o10] + w01*Fc[o01] + w11*Fc[o11];
            acc[c >> 2] = fmaf(s, refv[c], acc[c >> 2]);
        }
    }
    const float scale = 1.f / 12.f;
    #pragma unroll
    for (int g = 0; g < G; ++g)
        out[g*TOTAL + tid] = acc[g] * scale;
}

extern "C" void kernel_launch(void* const* d_in, const int* in_sizes, int n_in,
                              void* d_out, int out_size, void* d_ws, size_t ws_size,
                              hipStream_t stream) {
    const float* fea   = (const float*)d_in[0];
    const float* proj  = (const float*)d_in[1];
    const float* depth = (const float*)d_in[2];
    float* out = (float*)d_out;

    const size_t need = (size_t)NVIEW * HW * C * sizeof(float);  // 8.25 MB
    if (ws_size >= need) {
        float* feaT = (float*)d_ws;
        transpose_kernel<<<(NVIEW*HW)/256, 256, 0, stream>>>(fea, feaT);
        gwc_main<<<(HW*NDC*4)/256, 256, 0, stream>>>(feaT, proj, depth, out);
    } else {
        gwc_fallback<<<TOTAL/256, 256, 0, stream>>>(fea, proj, depth, out);
    }
}

// Round 3
// 72.621 us; speedup vs baseline: 2.8971x; 1.0814x over previous
//
#include <hip/hip_runtime.h>

// GroupWiseAgg: MVS group-wise correlation cost volume.
// features: (NVIEW=4, C=32, H=112, W=144) fp32
// proj:     (NVIEW, 2, 4, 4) fp32  [0]=extrinsic E, [1]=intrinsic K
// depth:    (D=48, H=112, W=144) fp32
// out:      (G=8, D, H, W) fp32
//
// R3: HWC features in ws; 4 lanes/pixel own 2 chunks each; per depth,
// ALL 24 tap loads issued before consumption (sched_barrier-pinned) to
// cut latency stalls from 3/depth to 1/depth. rcp instead of div.

constexpr int NVIEW = 4;
constexpr int C     = 32;
constexpr int G     = 8;
constexpr int D     = 48;
constexpr int H     = 112;
constexpr int W     = 144;
constexpr int HW    = H * W;        // 16128
constexpr int TOTAL = D * HW;       // 774144
constexpr int DCHUNK = 4;
constexpr int NDC    = D / DCHUNK;  // 12

// ---------- matrix helpers (thread-0 only) ----------
__device__ inline void fold_mat(const float* pm, double out[16]) {
    const float* E = pm;
    const float* K = pm + 16;
    for (int i = 0; i < 3; ++i)
        for (int j = 0; j < 4; ++j) {
            double s = 0.0;
            for (int k = 0; k < 3; ++k) s += (double)K[i*4+k] * (double)E[k*4+j];
            out[i*4+j] = s;
        }
    for (int j = 0; j < 4; ++j) out[12+j] = (double)E[12+j];
}

__device__ inline void inv4(const double A[16], double out[16]) {
    double M[4][8];
    for (int r = 0; r < 4; ++r) {
        for (int c = 0; c < 4; ++c) M[r][c] = A[r*4+c];
        for (int c = 0; c < 4; ++c) M[r][4+c] = (r == c) ? 1.0 : 0.0;
    }
    for (int col = 0; col < 4; ++col) {
        int piv = col;
        double best = fabs(M[col][col]);
        for (int r = col+1; r < 4; ++r) {
            double v = fabs(M[r][col]);
            if (v > best) { best = v; piv = r; }
        }
        if (piv != col)
            for (int c = 0; c < 8; ++c) { double t = M[col][c]; M[col][c] = M[piv][c]; M[piv][c] = t; }
        double ip = 1.0 / M[col][col];
        for (int c = 0; c < 8; ++c) M[col][c] *= ip;
        for (int r = 0; r < 4; ++r) {
            if (r == col) continue;
            double f = M[r][col];
            if (f != 0.0)
                for (int c = 0; c < 8; ++c) M[r][c] -= f * M[col][c];
        }
    }
    for (int r = 0; r < 4; ++r)
        for (int c = 0; c < 4; ++c) out[r*4+c] = M[r][4+c];
}

__device__ inline void compute_rt(const float* proj, float* dst) {
    double Pref[16], Pinv[16];
    fold_mat(proj, Pref);
    inv4(Pref, Pinv);
    for (int v = 1; v < NVIEW; ++v) {
        double Ps[16], Pr[16];
        fold_mat(proj + v*32, Ps);
        for (int i = 0; i < 4; ++i)
            for (int j = 0; j < 4; ++j) {
                double s = 0.0;
                for (int k = 0; k < 4; ++k) s += Ps[i*4+k] * Pinv[k*4+j];
                Pr[i*4+j] = s;
            }
        float* o = dst + (v-1)*12;
        for (int i = 0; i < 3; ++i)
            for (int j = 0; j < 3; ++j) o[i*3+j] = (float)Pr[i*4+j];
        for (int i = 0; i < 3; ++i) o[9+i] = (float)Pr[i*4+3];
    }
}

// ---------- transpose CHW -> HWC ----------
__global__ __launch_bounds__(256) void transpose_kernel(
    const float* __restrict__ fea, float* __restrict__ feaT)
{
    const int t = blockIdx.x * blockDim.x + threadIdx.x;  // v*HW + p
    const int v = t / HW;
    const int p = t - v * HW;
    const float* src = fea + v*(C*HW) + p;
    float vals[C];
    #pragma unroll
    for (int c = 0; c < C; ++c) vals[c] = src[c*HW];
    float4* dst = (float4*)(feaT + (size_t)t * C);
    #pragma unroll
    for (int q = 0; q < C/4; ++q)
        dst[q] = make_float4(vals[4*q], vals[4*q+1], vals[4*q+2], vals[4*q+3]);
}

// ---------- main kernel ----------
__global__ __launch_bounds__(256) void gwc_main(
    const float* __restrict__ feaT,   // (NVIEW, HW, C)
    const float* __restrict__ proj,   // (NVIEW, 2, 4, 4)
    const float* __restrict__ depth,  // (D, HW)
    float* __restrict__ out)          // (G, D, HW)
{
    __shared__ float s_rt[(NVIEW-1)*12];
    if (threadIdx.x == 0) compute_rt(proj, s_rt);
    __syncthreads();

    const int tid = blockIdx.x * blockDim.x + threadIdx.x;
    const int l   = tid & 3;        // owns groups l and l+4
    const int wid = tid >> 2;
    const int p   = wid % HW;
    const int dc  = wid / HW;
    const float fx = (float)(p % W);
    const float fy = (float)(p / W);

    const float4 refA = *(const float4*)(feaT + (size_t)p*C + l*4);
    const float4 refB = *(const float4*)(feaT + (size_t)p*C + (l+4)*4);

    float rx[3], ry[3], rz[3], tx[3], ty[3], tz[3];
    #pragma unroll
    for (int v = 0; v < 3; ++v) {
        const float* rt = s_rt + v*12;
        rx[v] = fmaf(rt[0], fx, fmaf(rt[1], fy, rt[2]));
        ry[v] = fmaf(rt[3], fx, fmaf(rt[4], fy, rt[5]));
        rz[v] = fmaf(rt[6], fx, fmaf(rt[7], fy, rt[8]));
        tx[v] = rt[9]; ty[v] = rt[10]; tz[v] = rt[11];
    }

    const float scale = 1.f / 12.f;

    for (int dd = 0; dd < DCHUNK; ++dd) {
        const int d    = dc * DCHUNK + dd;
        const int didx = d * HW + p;
        const float dep = depth[didx];

        float wts[3][4];
        float4 ta[3][4], tb[3][4];

        // ---- phase 1: coords + weights + issue ALL 24 tap loads ----
        #pragma unroll
        for (int v = 0; v < 3; ++v) {
            const float X = fmaf(rx[v], dep, tx[v]);
            const float Y = fmaf(ry[v], dep, ty[v]);
            const float Z = fmaf(rz[v], dep, tz[v]);
            const float iZ = __builtin_amdgcn_rcpf(Z);
            const float px = X * iZ;
            const float py = Y * iZ;

            const float x0f = floorf(px), y0f = floorf(py);
            const float dx = px - x0f, dy = py - y0f;
            const int x0 = (int)x0f, y0 = (int)y0f;
            const int x1 = x0 + 1,  y1 = y0 + 1;

            float w00 = (1.f-dx)*(1.f-dy);
            float w10 = dx*(1.f-dy);
            float w01 = (1.f-dx)*dy;
            float w11 = dx*dy;

            const bool vx0 = (x0 >= 0) & (x0 < W);
            const bool vx1 = (x1 >= 0) & (x1 < W);
            const bool vy0 = (y0 >= 0) & (y0 < H);
            const bool vy1 = (y1 >= 0) & (y1 < H);
            if (!(vx0 && vy0)) w00 = 0.f;
            if (!(vx1 && vy0)) w10 = 0.f;
            if (!(vx0 && vy1)) w01 = 0.f;
            if (!(vx1 && vy1)) w11 = 0.f;
            wts[v][0] = w00; wts[v][1] = w10; wts[v][2] = w01; wts[v][3] = w11;

            const int xc0 = min(max(x0, 0), W-1), xc1 = min(max(x1, 0), W-1);
            const int yc0 = min(max(y0, 0), H-1), yc1 = min(max(y1, 0), H-1);
            const int off[4] = { yc0*W + xc0, yc0*W + xc1, yc1*W + xc0, yc1*W + xc1 };

            const float* base = feaT + (size_t)(v+1) * HW * C;
            #pragma unroll
            for (int t = 0; t < 4; ++t) {
                const float4* tp = (const float4*)(base + (size_t)off[t]*C);
                ta[v][t] = tp[l];
                tb[v][t] = tp[l+4];
            }
        }

        // pin: loads above, consumption below
        __builtin_amdgcn_sched_barrier(0);

        // ---- phase 2: consume ----
        float accA = 0.f, accB = 0.f;
        #pragma unroll
        for (int v = 0; v < 3; ++v) {
            const float w00 = wts[v][0], w10 = wts[v][1], w01 = wts[v][2], w11 = wts[v][3];
            const float4 a0 = ta[v][0], a1 = ta[v][1], a2 = ta[v][2], a3 = ta[v][3];
            const float4 b0 = tb[v][0], b1 = tb[v][1], b2 = tb[v][2], b3 = tb[v][3];

            const float sAx = w00*a0.x + w10*a1.x + w01*a2.x + w11*a3.x;
            const float sAy = w00*a0.y + w10*a1.y + w01*a2.y + w11*a3.y;
            const float sAz = w00*a0.z + w10*a1.z + w01*a2.z + w11*a3.z;
            const float sAw = w00*a0.w + w10*a1.w + w01*a2.w + w11*a3.w;
            const float sBx = w00*b0.x + w10*b1.x + w01*b2.x + w11*b3.x;
            const float sBy = w00*b0.y + w10*b1.y + w01*b2.y + w11*b3.y;
            const float sBz = w00*b0.z + w10*b1.z + w01*b2.z + w11*b3.z;
            const float sBw = w00*b0.w + w10*b1.w + w01*b2.w + w11*b3.w;

            accA = fmaf(sAx, refA.x, fmaf(sAy, refA.y, fmaf(sAz, refA.z, fmaf(sAw, refA.w, accA))));
            accB = fmaf(sBx, refB.x, fmaf(sBy, refB.y, fmaf(sBz, refB.z, fmaf(sBw, refB.w, accB))));
        }

        __builtin_nontemporal_store(accA * scale, &out[l*TOTAL + didx]);
        __builtin_nontemporal_store(accB * scale, &out[(l+4)*TOTAL + didx]);
    }
}

// ---------- fallback if ws too small ----------
__global__ __launch_bounds__(256) void gwc_fallback(
    const float* __restrict__ fea,
    const float* __restrict__ proj,
    const float* __restrict__ depth,
    float* __restrict__ out)
{
    __shared__ float s_rt[(NVIEW-1)*12];
    if (threadIdx.x == 0) compute_rt(proj, s_rt);
    __syncthreads();

    const int tid = blockIdx.x * blockDim.x + threadIdx.x;
    const int p   = tid % HW;
    const float dep = depth[tid];
    const float fx = (float)(p % W);
    const float fy = (float)(p / W);

    float refv[C];
    #pragma unroll
    for (int c = 0; c < C; ++c) refv[c] = fea[c*HW + p];

    float acc[G];
    #pragma unroll
    for (int g = 0; g < G; ++g) acc[g] = 0.f;

    #pragma unroll
    for (int v = 1; v < NVIEW; ++v) {
        const float* rt = s_rt + (v-1)*12;
        const float X = fmaf(fmaf(rt[0], fx, fmaf(rt[1], fy, rt[2])), dep, rt[9]);
        const float Y = fmaf(fmaf(rt[3], fx, fmaf(rt[4], fy, rt[5])), dep, rt[10]);
        const float Z = fmaf(fmaf(rt[6], fx, fmaf(rt[7], fy, rt[8])), dep, rt[11]);
        const float px = X / Z, py = Y / Z;
        const float x0f = floorf(px), y0f = floorf(py);
        const float dx = px - x0f, dy = py - y0f;
        const int x0 = (int)x0f, y0 = (int)y0f;
        const int x1 = x0 + 1,  y1 = y0 + 1;
        float w00 = (1.f-dx)*(1.f-dy), w10 = dx*(1.f-dy), w01 = (1.f-dx)*dy, w11 = dx*dy;
        const bool vx0 = (x0 >= 0) & (x0 < W), vx1 = (x1 >= 0) & (x1 < W);
        const bool vy0 = (y0 >= 0) & (y0 < H), vy1 = (y1 >= 0) & (y1 < H);
        if (!(vx0 && vy0)) w00 = 0.f;
        if (!(vx1 && vy0)) w10 = 0.f;
        if (!(vx0 && vy1)) w01 = 0.f;
        if (!(vx1 && vy1)) w11 = 0.f;
        const int xc0 = min(max(x0, 0), W-1), xc1 = min(max(x1, 0), W-1);
        const int yc0 = min(max(y0, 0), H-1), yc1 = min(max(y1, 0), H-1);
        const int o00 = yc0*W + xc0, o10 = yc0*W + xc1;
        const int o01 = yc1*W + xc0, o11 = yc1*W + xc1;
        const float* Fv = fea + v*(C*HW);
        #pragma unroll
        for (int c = 0; c < C; ++c) {
            const float* Fc = Fv + c*HW;
            const float s = w00*Fc[o00] + w10*Fc[o10] + w01*Fc[o01] + w11*Fc[o11];
            acc[c >> 2] = fmaf(s, refv[c], acc[c >> 2]);
        }
    }
    const float scale = 1.f / 12.f;
    #pragma unroll
    for (int g = 0; g < G; ++g)
        out[g*TOTAL + tid] = acc[g] * scale;
}

extern "C" void kernel_launch(void* const* d_in, const int* in_sizes, int n_in,
                              void* d_out, int out_size, void* d_ws, size_t ws_size,
                              hipStream_t stream) {
    const float* fea   = (const float*)d_in[0];
    const float* proj  = (const float*)d_in[1];
    const float* depth = (const float*)d_in[2];
    float* out = (float*)d_out;

    const size_t need = (size_t)NVIEW * HW * C * sizeof(float);  // 8.25 MB
    if (ws_size >= need) {
        float* feaT = (float*)d_ws;
        transpose_kernel<<<(NVIEW*HW)/256, 256, 0, stream>>>(fea, feaT);
        gwc_main<<<(HW*NDC*4)/256, 256, 0, stream>>>(feaT, proj, depth, out);
    } else {
        gwc_fallback<<<TOTAL/256, 256, 0, stream>>>(fea, proj, depth, out);
    }
}

// Round 4
// 51.938 us; speedup vs baseline: 4.0509x; 1.3982x over previous
//
#include <hip/hip_runtime.h>

// GroupWiseAgg: MVS group-wise correlation cost volume.
// features: (NVIEW=4, C=32, H=112, W=144) fp32
// proj:     (NVIEW, 2, 4, 4) fp32  [0]=extrinsic E, [1]=intrinsic K
// depth:    (D=48, H=112, W=144) fp32
// out:      (G=8, D, H, W) fp32
//
// R4: fp16 HWC feature buffer (64B/pixel); 4 lanes/pixel each own 8 channels
// (= 2 groups); packed fp16 blend + v_dot2_f32_f16 accumulate; 2-deep
// software pipeline over depth (macro-expanded double buffers, all indices
// compile-time) so each wave waits vmcnt(12), not vmcnt(0).

typedef _Float16 h2  __attribute__((ext_vector_type(2)));
typedef _Float16 h8v __attribute__((ext_vector_type(8)));
struct __attribute__((aligned(16))) h2x4 { h2 x, y, z, w; };

constexpr int NVIEW = 4;
constexpr int C     = 32;
constexpr int D     = 48;
constexpr int H     = 112;
constexpr int W     = 144;
constexpr int HW    = H * W;        // 16128
constexpr int TOTAL = D * HW;       // 774144
constexpr int DCHUNK = 4;
constexpr int NDC    = D / DCHUNK;  // 12

#if __has_builtin(__builtin_amdgcn_fdot2)
__device__ inline float dot2f(h2 a, h2 b, float c) {
    return __builtin_amdgcn_fdot2(a, b, c, false);
}
#else
__device__ inline float dot2f(h2 a, h2 b, float c) {
    return fmaf((float)a.x, (float)b.x, fmaf((float)a.y, (float)b.y, c));
}
#endif

// ---------- matrix helpers (thread-0 only) ----------
__device__ inline void fold_mat(const float* pm, double out[16]) {
    const float* E = pm;
    const float* K = pm + 16;
    for (int i = 0; i < 3; ++i)
        for (int j = 0; j < 4; ++j) {
            double s = 0.0;
            for (int k = 0; k < 3; ++k) s += (double)K[i*4+k] * (double)E[k*4+j];
            out[i*4+j] = s;
        }
    for (int j = 0; j < 4; ++j) out[12+j] = (double)E[12+j];
}

__device__ inline void inv4(const double A[16], double out[16]) {
    double M[4][8];
    for (int r = 0; r < 4; ++r) {
        for (int c = 0; c < 4; ++c) M[r][c] = A[r*4+c];
        for (int c = 0; c < 4; ++c) M[r][4+c] = (r == c) ? 1.0 : 0.0;
    }
    for (int col = 0; col < 4; ++col) {
        int piv = col;
        double best = fabs(M[col][col]);
        for (int r = col+1; r < 4; ++r) {
            double v = fabs(M[r][col]);
            if (v > best) { best = v; piv = r; }
        }
        if (piv != col)
            for (int c = 0; c < 8; ++c) { double t = M[col][c]; M[col][c] = M[piv][c]; M[piv][c] = t; }
        double ip = 1.0 / M[col][col];
        for (int c = 0; c < 8; ++c) M[col][c] *= ip;
        for (int r = 0; r < 4; ++r) {
            if (r == col) continue;
            double f = M[r][col];
            if (f != 0.0)
                for (int c = 0; c < 8; ++c) M[r][c] -= f * M[col][c];
        }
    }
    for (int r = 0; r < 4; ++r)
        for (int c = 0; c < 4; ++c) out[r*4+c] = M[r][4+c];
}

__device__ inline void compute_rt(const float* proj, float* dst) {
    double Pref[16], Pinv[16];
    fold_mat(proj, Pref);
    inv4(Pref, Pinv);
    for (int v = 1; v < NVIEW; ++v) {
        double Ps[16], Pr[16];
        fold_mat(proj + v*32, Ps);
        for (int i = 0; i < 4; ++i)
            for (int j = 0; j < 4; ++j) {
                double s = 0.0;
                for (int k = 0; k < 4; ++k) s += Ps[i*4+k] * Pinv[k*4+j];
                Pr[i*4+j] = s;
            }
        float* o = dst + (v-1)*12;
        for (int i = 0; i < 3; ++i)
            for (int j = 0; j < 3; ++j) o[i*3+j] = (float)Pr[i*4+j];
        for (int i = 0; i < 3; ++i) o[9+i] = (float)Pr[i*4+3];
    }
}

// ---------- transpose CHW fp32 -> HWC fp16 ----------
__global__ __launch_bounds__(256) void transpose_h(
    const float* __restrict__ fea, _Float16* __restrict__ feaH)
{
    const int t = blockIdx.x * blockDim.x + threadIdx.x;  // v*HW + p
    const int v = t / HW;
    const int p = t - v * HW;
    const float* src = fea + (size_t)v*C*HW + p;
    h8v ov[4];
    #pragma unroll
    for (int q = 0; q < 4; ++q) {
        #pragma unroll
        for (int k = 0; k < 8; ++k) ov[q][k] = (_Float16)src[(q*8+k)*HW];
    }
    h8v* dst = (h8v*)(feaH + (size_t)t * C);
    #pragma unroll
    for (int q = 0; q < 4; ++q) dst[q] = ov[q];
}

// ---------- main kernel ----------
#define PREP(DD, BUF) { \
    const float dep_ = deps[DD]; \
    _Pragma("unroll") \
    for (int v_ = 0; v_ < 3; ++v_) { \
        const float X_ = fmaf(rx[v_], dep_, tx[v_]); \
        const float Y_ = fmaf(ry[v_], dep_, ty[v_]); \
        const float Z_ = fmaf(rz[v_], dep_, tz[v_]); \
        const float iZ_ = __builtin_amdgcn_rcpf(Z_); \
        const float px_ = X_ * iZ_, py_ = Y_ * iZ_; \
        const float x0f_ = floorf(px_), y0f_ = floorf(py_); \
        const float dx_ = px_ - x0f_, dy_ = py_ - y0f_; \
        const int x0_ = (int)x0f_, y0_ = (int)y0f_; \
        const int x1_ = x0_ + 1,  y1_ = y0_ + 1; \
        float w00_ = (1.f-dx_)*(1.f-dy_); \
        float w10_ = dx_*(1.f-dy_); \
        float w01_ = (1.f-dx_)*dy_; \
        float w11_ = dx_*dy_; \
        const bool vx0_ = (x0_ >= 0) & (x0_ < W); \
        const bool vx1_ = (x1_ >= 0) & (x1_ < W); \
        const bool vy0_ = (y0_ >= 0) & (y0_ < H); \
        const bool vy1_ = (y1_ >= 0) & (y1_ < H); \
        if (!(vx0_ && vy0_)) w00_ = 0.f; \
        if (!(vx1_ && vy0_)) w10_ = 0.f; \
        if (!(vx0_ && vy1_)) w01_ = 0.f; \
        if (!(vx1_ && vy1_)) w11_ = 0.f; \
        const int xc0_ = min(max(x0_,0),W-1), xc1_ = min(max(x1_,0),W-1); \
        const int yc0_ = min(max(y0_,0),H-1), yc1_ = min(max(y1_,0),H-1); \
        const int off_[4] = { yc0_*W+xc0_, yc0_*W+xc1_, yc1_*W+xc0_, yc1_*W+xc1_ }; \
        const float wf_[4] = { w00_, w10_, w01_, w11_ }; \
        const _Float16* base_ = feaH + (size_t)(v_+1)*HW*C + l*8; \
        _Pragma("unroll") \
        for (int t_ = 0; t_ < 4; ++t_) { \
            taps[BUF][v_][t_] = *(const h2x4*)(base_ + (size_t)off_[t_]*C); \
            const _Float16 wh_ = (_Float16)wf_[t_]; \
            h2 wt_; wt_.x = wh_; wt_.y = wh_; \
            wgt[BUF][v_][t_] = wt_; \
        } \
    } \
}

#define CONS(DD, BUF) { \
    float accA_ = 0.f, accB_ = 0.f; \
    _Pragma("unroll") \
    for (int v_ = 0; v_ < 3; ++v_) { \
        h2 s0_ = wgt[BUF][v_][0] * taps[BUF][v_][0].x; \
        h2 s1_ = wgt[BUF][v_][0] * taps[BUF][v_][0].y; \
        h2 s2_ = wgt[BUF][v_][0] * taps[BUF][v_][0].z; \
        h2 s3_ = wgt[BUF][v_][0] * taps[BUF][v_][0].w; \
        _Pragma("unroll") \
        for (int t_ = 1; t_ < 4; ++t_) { \
            s0_ += wgt[BUF][v_][t_] * taps[BUF][v_][t_].x; \
            s1_ += wgt[BUF][v_][t_] * taps[BUF][v_][t_].y; \
            s2_ += wgt[BUF][v_][t_] * taps[BUF][v_][t_].z; \
            s3_ += wgt[BUF][v_][t_] * taps[BUF][v_][t_].w; \
        } \
        accA_ = dot2f(s0_, refq.x, accA_); \
        accA_ = dot2f(s1_, refq.y, accA_); \
        accB_ = dot2f(s2_, refq.z, accB_); \
        accB_ = dot2f(s3_, refq.w, accB_); \
    } \
    const int didx_ = (dc*DCHUNK + (DD))*HW + p; \
    __builtin_nontemporal_store(accA_ * scale, &out[(2*l  )*TOTAL + didx_]); \
    __builtin_nontemporal_store(accB_ * scale, &out[(2*l+1)*TOTAL + didx_]); \
}

__global__ __launch_bounds__(256) void gwc_main(
    const _Float16* __restrict__ feaH,  // (NVIEW, HW, C) fp16
    const float* __restrict__ proj,     // (NVIEW, 2, 4, 4)
    const float* __restrict__ depth,    // (D, HW)
    float* __restrict__ out)            // (G=8, D, HW)
{
    __shared__ float s_rt[(NVIEW-1)*12];
    if (threadIdx.x == 0) compute_rt(proj, s_rt);
    __syncthreads();

    const int tid = blockIdx.x * blockDim.x + threadIdx.x;
    const int l   = tid & 3;        // channel octet: owns groups 2l, 2l+1
    const int wid = tid >> 2;
    const int p   = wid % HW;
    const int dc  = wid / HW;
    const float fx = (float)(p % W);
    const float fy = (float)(p / W);

    const h2x4 refq = *(const h2x4*)(feaH + (size_t)p*C + l*8);

    float rx[3], ry[3], rz[3], tx[3], ty[3], tz[3];
    #pragma unroll
    for (int v = 0; v < 3; ++v) {
        const float* rt = s_rt + v*12;
        rx[v] = fmaf(rt[0], fx, fmaf(rt[1], fy, rt[2]));
        ry[v] = fmaf(rt[3], fx, fmaf(rt[4], fy, rt[5]));
        rz[v] = fmaf(rt[6], fx, fmaf(rt[7], fy, rt[8]));
        tx[v] = rt[9]; ty[v] = rt[10]; tz[v] = rt[11];
    }

    float deps[DCHUNK];
    #pragma unroll
    for (int dd = 0; dd < DCHUNK; ++dd)
        deps[dd] = depth[(dc*DCHUNK + dd)*HW + p];

    h2x4 taps[2][3][4];
    h2   wgt[2][3][4];
    const float scale = 1.f / 12.f;

    PREP(0, 0)
    PREP(1, 1)
    __builtin_amdgcn_sched_barrier(0);
    CONS(0, 0)
    PREP(2, 0)
    __builtin_amdgcn_sched_barrier(0);
    CONS(1, 1)
    PREP(3, 1)
    __builtin_amdgcn_sched_barrier(0);
    CONS(2, 0)
    CONS(3, 1)
}

// ---------- fallback if ws too small (fp32 direct CHW) ----------
__global__ __launch_bounds__(256) void gwc_fallback(
    const float* __restrict__ fea,
    const float* __restrict__ proj,
    const float* __restrict__ depth,
    float* __restrict__ out)
{
    __shared__ float s_rt[(NVIEW-1)*12];
    if (threadIdx.x == 0) compute_rt(proj, s_rt);
    __syncthreads();

    const int tid = blockIdx.x * blockDim.x + threadIdx.x;
    const int p   = tid % HW;
    const float dep = depth[tid];
    const float fx = (float)(p % W);
    const float fy = (float)(p / W);

    float refv[C];
    #pragma unroll
    for (int c = 0; c < C; ++c) refv[c] = fea[c*HW + p];

    float acc[8];
    #pragma unroll
    for (int g = 0; g < 8; ++g) acc[g] = 0.f;

    #pragma unroll
    for (int v = 1; v < NVIEW; ++v) {
        const float* rt = s_rt + (v-1)*12;
        const float X = fmaf(fmaf(rt[0], fx, fmaf(rt[1], fy, rt[2])), dep, rt[9]);
        const float Y = fmaf(fmaf(rt[3], fx, fmaf(rt[4], fy, rt[5])), dep, rt[10]);
        const float Z = fmaf(fmaf(rt[6], fx, fmaf(rt[7], fy, rt[8])), dep, rt[11]);
        const float px = X / Z, py = Y / Z;
        const float x0f = floorf(px), y0f = floorf(py);
        const float dx = px - x0f, dy = py - y0f;
        const int x0 = (int)x0f, y0 = (int)y0f;
        const int x1 = x0 + 1,  y1 = y0 + 1;
        float w00 = (1.f-dx)*(1.f-dy), w10 = dx*(1.f-dy), w01 = (1.f-dx)*dy, w11 = dx*dy;
        const bool vx0 = (x0 >= 0) & (x0 < W), vx1 = (x1 >= 0) & (x1 < W);
        const bool vy0 = (y0 >= 0) & (y0 < H), vy1 = (y1 >= 0) & (y1 < H);
        if (!(vx0 && vy0)) w00 = 0.f;
        if (!(vx1 && vy0)) w10 = 0.f;
        if (!(vx0 && vy1)) w01 = 0.f;
        if (!(vx1 && vy1)) w11 = 0.f;
        const int xc0 = min(max(x0, 0), W-1), xc1 = min(max(x1, 0), W-1);
        const int yc0 = min(max(y0, 0), H-1), yc1 = min(max(y1, 0), H-1);
        const int o00 = yc0*W + xc0, o10 = yc0*W + xc1;
        const int o01 = yc1*W + xc0, o11 = yc1*W + xc1;
        const float* Fv = fea + v*(C*HW);
        #pragma unroll
        for (int c = 0; c < C; ++c) {
            const float* Fc = Fv + c*HW;
            const float s = w00*Fc[o00] + w10*Fc[o10] + w01*Fc[o01] + w11*Fc[o11];
            acc[c >> 2] = fmaf(s, refv[c], acc[c >> 2]);
        }
    }
    const float scale = 1.f / 12.f;
    #pragma unroll
    for (int g = 0; g < 8; ++g)
        out[g*TOTAL + tid] = acc[g] * scale;
}

extern "C" void kernel_launch(void* const* d_in, const int* in_sizes, int n_in,
                              void* d_out, int out_size, void* d_ws, size_t ws_size,
                              hipStream_t stream) {
    const float* fea   = (const float*)d_in[0];
    const float* proj  = (const float*)d_in[1];
    const float* depth = (const float*)d_in[2];
    float* out = (float*)d_out;

    const size_t need = (size_t)NVIEW * HW * C * sizeof(_Float16);  // 4.13 MB
    if (ws_size >= need) {
        _Float16* feaH = (_Float16*)d_ws;
        transpose_h<<<(NVIEW*HW)/256, 256, 0, stream>>>(fea, feaH);
        gwc_main<<<(HW*NDC*4)/256, 256, 0, stream>>>(feaH, proj, depth, out);
    } else {
        gwc_fallback<<<TOTAL/256, 256, 0, stream>>>(fea, proj, depth, out);
    }
}

// Round 5
// 50.145 us; speedup vs baseline: 4.1957x; 1.0358x over previous
//
#include <hip/hip_runtime.h>

// GroupWiseAgg: MVS group-wise correlation cost volume.
// features: (NVIEW=4, C=32, H=112, W=144) fp32
// proj:     (NVIEW, 2, 4, 4) fp32  [0]=extrinsic E, [1]=intrinsic K
// depth:    (D=48, H=112, W=144) fp32
// out:      (G=8, D, H, W) fp32
//
// R5: R4 (fp16 HWC taps, 2-deep depth pipeline) + XCD band partitioning:
// physical block b -> xcd = b%8 owns pixel rows [xcd*14, xcd*14+14) for ALL
// depth chunks, so each XCD's L2 working set is ~2 MB (fits 4 MB L2)
// instead of the whole 4.1 MB feature buffer + streams.

typedef _Float16 h2  __attribute__((ext_vector_type(2)));
typedef _Float16 h8v __attribute__((ext_vector_type(8)));
struct __attribute__((aligned(16))) h2x4 { h2 x, y, z, w; };

constexpr int NVIEW = 4;
constexpr int C     = 32;
constexpr int D     = 48;
constexpr int H     = 112;
constexpr int W     = 144;
constexpr int HW    = H * W;        // 16128
constexpr int TOTAL = D * HW;       // 774144
constexpr int DCHUNK = 4;
constexpr int NDC    = D / DCHUNK;  // 12
constexpr int NXCD   = 8;
constexpr int BAND   = HW / NXCD;   // 2016 pixels (14 rows)
constexpr int WPB    = 64;          // wids per block (256 threads / 4 lanes)
constexpr int BLK_PER_XCD = (BAND * NDC) / WPB;  // 378

#if __has_builtin(__builtin_amdgcn_fdot2)
__device__ inline float dot2f(h2 a, h2 b, float c) {
    return __builtin_amdgcn_fdot2(a, b, c, false);
}
#else
__device__ inline float dot2f(h2 a, h2 b, float c) {
    return fmaf((float)a.x, (float)b.x, fmaf((float)a.y, (float)b.y, c));
}
#endif

// ---------- matrix helpers (thread-0 only) ----------
__device__ inline void fold_mat(const float* pm, double out[16]) {
    const float* E = pm;
    const float* K = pm + 16;
    for (int i = 0; i < 3; ++i)
        for (int j = 0; j < 4; ++j) {
            double s = 0.0;
            for (int k = 0; k < 3; ++k) s += (double)K[i*4+k] * (double)E[k*4+j];
            out[i*4+j] = s;
        }
    for (int j = 0; j < 4; ++j) out[12+j] = (double)E[12+j];
}

__device__ inline void inv4(const double A[16], double out[16]) {
    double M[4][8];
    for (int r = 0; r < 4; ++r) {
        for (int c = 0; c < 4; ++c) M[r][c] = A[r*4+c];
        for (int c = 0; c < 4; ++c) M[r][4+c] = (r == c) ? 1.0 : 0.0;
    }
    for (int col = 0; col < 4; ++col) {
        int piv = col;
        double best = fabs(M[col][col]);
        for (int r = col+1; r < 4; ++r) {
            double v = fabs(M[r][col]);
            if (v > best) { best = v; piv = r; }
        }
        if (piv != col)
            for (int c = 0; c < 8; ++c) { double t = M[col][c]; M[col][c] = M[piv][c]; M[piv][c] = t; }
        double ip = 1.0 / M[col][col];
        for (int c = 0; c < 8; ++c) M[col][c] *= ip;
        for (int r = 0; r < 4; ++r) {
            if (r == col) continue;
            double f = M[r][col];
            if (f != 0.0)
                for (int c = 0; c < 8; ++c) M[r][c] -= f * M[col][c];
        }
    }
    for (int r = 0; r < 4; ++r)
        for (int c = 0; c < 4; ++c) out[r*4+c] = M[r][4+c];
}

__device__ inline void compute_rt(const float* proj, float* dst) {
    double Pref[16], Pinv[16];
    fold_mat(proj, Pref);
    inv4(Pref, Pinv);
    for (int v = 1; v < NVIEW; ++v) {
        double Ps[16], Pr[16];
        fold_mat(proj + v*32, Ps);
        for (int i = 0; i < 4; ++i)
            for (int j = 0; j < 4; ++j) {
                double s = 0.0;
                for (int k = 0; k < 4; ++k) s += Ps[i*4+k] * Pinv[k*4+j];
                Pr[i*4+j] = s;
            }
        float* o = dst + (v-1)*12;
        for (int i = 0; i < 3; ++i)
            for (int j = 0; j < 3; ++j) o[i*3+j] = (float)Pr[i*4+j];
        for (int i = 0; i < 3; ++i) o[9+i] = (float)Pr[i*4+3];
    }
}

// ---------- transpose CHW fp32 -> HWC fp16 ----------
__global__ __launch_bounds__(256) void transpose_h(
    const float* __restrict__ fea, _Float16* __restrict__ feaH)
{
    const int t = blockIdx.x * blockDim.x + threadIdx.x;  // v*HW + p
    const int v = t / HW;
    const int p = t - v * HW;
    const float* src = fea + (size_t)v*C*HW + p;
    h8v ov[4];
    #pragma unroll
    for (int q = 0; q < 4; ++q) {
        #pragma unroll
        for (int k = 0; k < 8; ++k) ov[q][k] = (_Float16)src[(q*8+k)*HW];
    }
    h8v* dst = (h8v*)(feaH + (size_t)t * C);
    #pragma unroll
    for (int q = 0; q < 4; ++q) dst[q] = ov[q];
}

// ---------- main kernel ----------
#define PREP(DD, BUF) { \
    const float dep_ = deps[DD]; \
    _Pragma("unroll") \
    for (int v_ = 0; v_ < 3; ++v_) { \
        const float X_ = fmaf(rx[v_], dep_, tx[v_]); \
        const float Y_ = fmaf(ry[v_], dep_, ty[v_]); \
        const float Z_ = fmaf(rz[v_], dep_, tz[v_]); \
        const float iZ_ = __builtin_amdgcn_rcpf(Z_); \
        const float px_ = X_ * iZ_, py_ = Y_ * iZ_; \
        const float x0f_ = floorf(px_), y0f_ = floorf(py_); \
        const float dx_ = px_ - x0f_, dy_ = py_ - y0f_; \
        const int x0_ = (int)x0f_, y0_ = (int)y0f_; \
        const int x1_ = x0_ + 1,  y1_ = y0_ + 1; \
        float w00_ = (1.f-dx_)*(1.f-dy_); \
        float w10_ = dx_*(1.f-dy_); \
        float w01_ = (1.f-dx_)*dy_; \
        float w11_ = dx_*dy_; \
        const bool vx0_ = (x0_ >= 0) & (x0_ < W); \
        const bool vx1_ = (x1_ >= 0) & (x1_ < W); \
        const bool vy0_ = (y0_ >= 0) & (y0_ < H); \
        const bool vy1_ = (y1_ >= 0) & (y1_ < H); \
        if (!(vx0_ && vy0_)) w00_ = 0.f; \
        if (!(vx1_ && vy0_)) w10_ = 0.f; \
        if (!(vx0_ && vy1_)) w01_ = 0.f; \
        if (!(vx1_ && vy1_)) w11_ = 0.f; \
        const int xc0_ = min(max(x0_,0),W-1), xc1_ = min(max(x1_,0),W-1); \
        const int yc0_ = min(max(y0_,0),H-1), yc1_ = min(max(y1_,0),H-1); \
        const int off_[4] = { yc0_*W+xc0_, yc0_*W+xc1_, yc1_*W+xc0_, yc1_*W+xc1_ }; \
        const float wf_[4] = { w00_, w10_, w01_, w11_ }; \
        const _Float16* base_ = feaH + (size_t)(v_+1)*HW*C + l*8; \
        _Pragma("unroll") \
        for (int t_ = 0; t_ < 4; ++t_) { \
            taps[BUF][v_][t_] = *(const h2x4*)(base_ + (size_t)off_[t_]*C); \
            const _Float16 wh_ = (_Float16)wf_[t_]; \
            h2 wt_; wt_.x = wh_; wt_.y = wh_; \
            wgt[BUF][v_][t_] = wt_; \
        } \
    } \
}

#define CONS(DD, BUF) { \
    float accA_ = 0.f, accB_ = 0.f; \
    _Pragma("unroll") \
    for (int v_ = 0; v_ < 3; ++v_) { \
        h2 s0_ = wgt[BUF][v_][0] * taps[BUF][v_][0].x; \
        h2 s1_ = wgt[BUF][v_][0] * taps[BUF][v_][0].y; \
        h2 s2_ = wgt[BUF][v_][0] * taps[BUF][v_][0].z; \
        h2 s3_ = wgt[BUF][v_][0] * taps[BUF][v_][0].w; \
        _Pragma("unroll") \
        for (int t_ = 1; t_ < 4; ++t_) { \
            s0_ += wgt[BUF][v_][t_] * taps[BUF][v_][t_].x; \
            s1_ += wgt[BUF][v_][t_] * taps[BUF][v_][t_].y; \
            s2_ += wgt[BUF][v_][t_] * taps[BUF][v_][t_].z; \
            s3_ += wgt[BUF][v_][t_] * taps[BUF][v_][t_].w; \
        } \
        accA_ = dot2f(s0_, refq.x, accA_); \
        accA_ = dot2f(s1_, refq.y, accA_); \
        accB_ = dot2f(s2_, refq.z, accB_); \
        accB_ = dot2f(s3_, refq.w, accB_); \
    } \
    const int didx_ = (dc*DCHUNK + (DD))*HW + p; \
    __builtin_nontemporal_store(accA_ * scale, &out[(2*l  )*TOTAL + didx_]); \
    __builtin_nontemporal_store(accB_ * scale, &out[(2*l+1)*TOTAL + didx_]); \
}

__global__ __launch_bounds__(256) void gwc_main(
    const _Float16* __restrict__ feaH,  // (NVIEW, HW, C) fp16
    const float* __restrict__ proj,     // (NVIEW, 2, 4, 4)
    const float* __restrict__ depth,    // (D, HW)
    float* __restrict__ out)            // (G=8, D, HW)
{
    __shared__ float s_rt[(NVIEW-1)*12];
    if (threadIdx.x == 0) compute_rt(proj, s_rt);
    __syncthreads();

    // XCD band partition: xcd = b%8 owns pixel band [xcd*BAND, (xcd+1)*BAND)
    // for ALL depth chunks -> per-XCD L2 working set ~2 MB.
    const int b    = blockIdx.x;
    const int xcd  = b % NXCD;
    const int j    = b / NXCD;                     // 0..377
    const int wloc = j * WPB + (threadIdx.x >> 2); // 0..24191 within band
    const int l    = threadIdx.x & 3;              // channel octet: groups 2l, 2l+1
    const int ploc = wloc % BAND;
    const int dc   = wloc / BAND;                  // 0..11
    const int p    = xcd * BAND + ploc;

    const float fx = (float)(p % W);
    const float fy = (float)(p / W);

    const h2x4 refq = *(const h2x4*)(feaH + (size_t)p*C + l*8);

    float rx[3], ry[3], rz[3], tx[3], ty[3], tz[3];
    #pragma unroll
    for (int v = 0; v < 3; ++v) {
        const float* rt = s_rt + v*12;
        rx[v] = fmaf(rt[0], fx, fmaf(rt[1], fy, rt[2]));
        ry[v] = fmaf(rt[3], fx, fmaf(rt[4], fy, rt[5]));
        rz[v] = fmaf(rt[6], fx, fmaf(rt[7], fy, rt[8]));
        tx[v] = rt[9]; ty[v] = rt[10]; tz[v] = rt[11];
    }

    float deps[DCHUNK];
    #pragma unroll
    for (int dd = 0; dd < DCHUNK; ++dd)
        deps[dd] = depth[(dc*DCHUNK + dd)*HW + p];

    h2x4 taps[2][3][4];
    h2   wgt[2][3][4];
    const float scale = 1.f / 12.f;

    PREP(0, 0)
    PREP(1, 1)
    __builtin_amdgcn_sched_barrier(0);
    CONS(0, 0)
    PREP(2, 0)
    __builtin_amdgcn_sched_barrier(0);
    CONS(1, 1)
    PREP(3, 1)
    __builtin_amdgcn_sched_barrier(0);
    CONS(2, 0)
    CONS(3, 1)
}

// ---------- fallback if ws too small (fp32 direct CHW) ----------
__global__ __launch_bounds__(256) void gwc_fallback(
    const float* __restrict__ fea,
    const float* __restrict__ proj,
    const float* __restrict__ depth,
    float* __restrict__ out)
{
    __shared__ float s_rt[(NVIEW-1)*12];
    if (threadIdx.x == 0) compute_rt(proj, s_rt);
    __syncthreads();

    const int tid = blockIdx.x * blockDim.x + threadIdx.x;
    const int p   = tid % HW;
    const float dep = depth[tid];
    const float fx = (float)(p % W);
    const float fy = (float)(p / W);

    float refv[C];
    #pragma unroll
    for (int c = 0; c < C; ++c) refv[c] = fea[c*HW + p];

    float acc[8];
    #pragma unroll
    for (int g = 0; g < 8; ++g) acc[g] = 0.f;

    #pragma unroll
    for (int v = 1; v < NVIEW; ++v) {
        const float* rt = s_rt + (v-1)*12;
        const float X = fmaf(fmaf(rt[0], fx, fmaf(rt[1], fy, rt[2])), dep, rt[9]);
        const float Y = fmaf(fmaf(rt[3], fx, fmaf(rt[4], fy, rt[5])), dep, rt[10]);
        const float Z = fmaf(fmaf(rt[6], fx, fmaf(rt[7], fy, rt[8])), dep, rt[11]);
        const float px = X / Z, py = Y / Z;
        const float x0f = floorf(px), y0f = floorf(py);
        const float dx = px - x0f, dy = py - y0f;
        const int x0 = (int)x0f, y0 = (int)y0f;
        const int x1 = x0 + 1,  y1 = y0 + 1;
        float w00 = (1.f-dx)*(1.f-dy), w10 = dx*(1.f-dy), w01 = (1.f-dx)*dy, w11 = dx*dy;
        const bool vx0 = (x0 >= 0) & (x0 < W), vx1 = (x1 >= 0) & (x1 < W);
        const bool vy0 = (y0 >= 0) & (y0 < H), vy1 = (y1 >= 0) & (y1 < H);
        if (!(vx0 && vy0)) w00 = 0.f;
        if (!(vx1 && vy0)) w10 = 0.f;
        if (!(vx0 && vy1)) w01 = 0.f;
        if (!(vx1 && vy1)) w11 = 0.f;
        const int xc0 = min(max(x0, 0), W-1), xc1 = min(max(x1, 0), W-1);
        const int yc0 = min(max(y0, 0), H-1), yc1 = min(max(y1, 0), H-1);
        const int o00 = yc0*W + xc0, o10 = yc0*W + xc1;
        const int o01 = yc1*W + xc0, o11 = yc1*W + xc1;
        const float* Fv = fea + v*(C*HW);
        #pragma unroll
        for (int c = 0; c < C; ++c) {
            const float* Fc = Fv + c*HW;
            const float s = w00*Fc[o00] + w10*Fc[o10] + w01*Fc[o01] + w11*Fc[o11];
            acc[c >> 2] = fmaf(s, refv[c], acc[c >> 2]);
        }
    }
    const float scale = 1.f / 12.f;
    #pragma unroll
    for (int g = 0; g < 8; ++g)
        out[g*TOTAL + tid] = acc[g] * scale;
}

extern "C" void kernel_launch(void* const* d_in, const int* in_sizes, int n_in,
                              void* d_out, int out_size, void* d_ws, size_t ws_size,
                              hipStream_t stream) {
    const float* fea   = (const float*)d_in[0];
    const float* proj  = (const float*)d_in[1];
    const float* depth = (const float*)d_in[2];
    float* out = (float*)d_out;

    const size_t need = (size_t)NVIEW * HW * C * sizeof(_Float16);  // 4.13 MB
    if (ws_size >= need) {
        _Float16* feaH = (_Float16*)d_ws;
        transpose_h<<<(NVIEW*HW)/256, 256, 0, stream>>>(fea, feaH);
        gwc_main<<<NXCD * BLK_PER_XCD, 256, 0, stream>>>(feaH, proj, depth, out);
    } else {
        gwc_fallback<<<TOTAL/256, 256, 0, stream>>>(fea, proj, depth, out);
    }
}